// Round 5
// baseline (95235.474 us; speedup 1.0000x reference)
//
#include <hip/hip_runtime.h>
#include <hip/hip_fp16.h>
#include <math.h>

// ---------------------------------------------------------------------------
// FARGAN core. B=128, T=504, nb_frames=500, steps=2000, SUB=40.
// Round 5: round-4 fp16/fdot2 structure +
//   (a) cross-phase weight prefetch (loads issued one phase early, static addrs)
//   (b) g2_hh + glu2 weights LDS-resident (131 KB LDS stash, 1 block/CU)
// ---------------------------------------------------------------------------

#define DEV __device__ __forceinline__

DEV float sigm(float x) { return 1.0f / (1.0f + __expf(-x)); }
DEV float tanh_f(float x) { return 1.0f - 2.0f / (__expf(2.0f * x) + 1.0f); }

typedef _Float16 h2v __attribute__((ext_vector_type(2)));

#if defined(__has_builtin)
#if __has_builtin(__builtin_amdgcn_fdot2)
#define HAVE_FDOT2 1
#endif
#endif

DEV float fdot2(h2v a, h2v b, float c) {
#ifdef HAVE_FDOT2
    return __builtin_amdgcn_fdot2(a, b, c, false);
#else
    return c + (float)a[0] * (float)b[0] + (float)a[1] * (float)b[1];
#endif
}

// ---- workspace layout (float offsets) ----
constexpr size_t STEPS = 2000;
constexpr size_t OFF_X     = 0;          // 128*502*64 f32
constexpr size_t OFF_Y     = 4200000;    // 128*500*128 f32
constexpr size_t OFF_GAIN  = 12392000;   // 128*2000 f32
constexpr size_t OFF_CONDH = 12648000;   // 128*500*320 halves
constexpr size_t OFF_W     = 22888000;   // fp16 weights

// packed fp16 weights: OUT*KPAD halves, layout uint4[(k/8)*OUT + j]
constexpr size_t W_FWC     = 0;                       // 192 x 352
constexpr size_t W_FWCGLU  = W_FWC    + 192*352;      // 192 x 192
constexpr size_t W_GOUT    = W_FWCGLU + 192*192;      // 4   x 192
constexpr size_t W_G1IH    = W_GOUT   + 4*192;        // 480 x 272
constexpr size_t W_G1HH    = W_G1IH   + 480*272;      // 480 x 160
constexpr size_t W_GLU1    = W_G1HH   + 480*160;      // 160 x 160
constexpr size_t W_G2IH    = W_GLU1   + 160*160;      // 384 x 240
constexpr size_t W_G2HH    = W_G2IH   + 384*240;      // 384 x 128   (LDS-resident)
constexpr size_t W_GLU2    = W_G2HH   + 384*128;      // 128 x 128   (LDS-resident)
constexpr size_t W_G3IH    = W_GLU2   + 128*128;      // 384 x 208
constexpr size_t W_G3HH    = W_G3IH   + 384*208;      // 384 x 128
constexpr size_t W_GLU3    = W_G3HH   + 384*128;      // 128 x 128
constexpr size_t W_SKIP    = W_GLU3   + 128*128;      // 128 x 704
constexpr size_t W_SKIPGLU = W_SKIP   + 128*704;      // 128 x 128
constexpr size_t W_SIG     = W_SKIPGLU+ 128*128;      // 40  x 128

// LDS weight stash offsets (uint4 units)
constexpr int WL_G2HH = 0;      // 16*384 = 6144 uint4
constexpr int WL_GLU2 = 6144;   // 16*128 = 2048 uint4
constexpr int WL_TOT  = 8192;   // 128 KiB

// ---------------------------------------------------------------------------
__global__ void k_pack_h(const float* __restrict__ src, __half* __restrict__ dst,
                         int OUT, int K, int KP8) {
    int t = blockIdx.x * 256 + threadIdx.x;
    if (t >= OUT * KP8) return;
    int j = t % OUT;
    int k8 = t / OUT;
    __half* d = dst + (size_t)t * 8;
#pragma unroll
    for (int i = 0; i < 8; ++i) {
        int k = k8 * 8 + i;
        d[i] = (k < K) ? __float2half(src[(size_t)j * K + k]) : __float2half(0.0f);
    }
}

// ---------------------------------------------------------------------------
// frontend (unchanged)
// ---------------------------------------------------------------------------
__global__ void k_feat(const float* __restrict__ features, const int* __restrict__ period,
                       const float* __restrict__ pembed, const float* __restrict__ fd1,
                       float* __restrict__ xbuf) {
    int t = blockIdx.x * 256 + threadIdx.x;
    const int total = 128 * 502 * 64;
    if (t >= total) return;
    int o = t & 63;
    int r = t >> 6;
    int ft = r % 502;
    int b = r / 502;
    const float* f = features + ((size_t)b * 504 + ft + 2) * 20;
    int per = period[b * 504 + ft + 2];
    per = min(max(per, 32), 254);
    const float* pe = pembed + (per - 32) * 12;
    const float* w = fd1 + o * 32;
    float acc = 0.0f;
#pragma unroll
    for (int i = 0; i < 20; ++i) acc += f[i] * w[i];
#pragma unroll
    for (int i = 0; i < 12; ++i) acc += pe[i] * w[20 + i];
    xbuf[t] = tanh_f(acc);
}

__global__ void k_conv(const float* __restrict__ xbuf, const float* __restrict__ fconv1,
                       float* __restrict__ ybuf) {
    int t = blockIdx.x * 256 + threadIdx.x;
    const int total = 128 * 500 * 128;
    if (t >= total) return;
    int oc = t & 127;
    int r = t >> 7;
    int tt = r % 500;
    int b = r / 500;
    const float* xp = xbuf + ((size_t)b * 502 + tt) * 64;
    const float* w = fconv1 + oc * 192;
    float acc = 0.0f;
#pragma unroll 8
    for (int i = 0; i < 64; ++i) {
        acc += xp[i] * w[i * 3 + 0];
        acc += xp[64 + i] * w[i * 3 + 1];
        acc += xp[128 + i] * w[i * 3 + 2];
    }
    ybuf[t] = tanh_f(acc);
}

__global__ void k_cond(const float* __restrict__ ybuf, const float* __restrict__ fd2,
                       __half* __restrict__ cond) {
    int b = blockIdx.x / 50;
    int t0 = (blockIdx.x % 50) * 10;
    int tid = threadIdx.x;
    __shared__ float yl[1280];
    for (int i = tid; i < 1280; i += 320)
        yl[i] = ybuf[((size_t)b * 500 + t0) * 128 + i];
    __syncthreads();
    const float* w = fd2 + tid * 128;
    float acc[10];
#pragma unroll
    for (int q = 0; q < 10; ++q) acc[q] = 0.0f;
#pragma unroll 4
    for (int k = 0; k < 128; ++k) {
        float wv = w[k];
#pragma unroll
        for (int q = 0; q < 10; ++q) acc[q] += wv * yl[q * 128 + k];
    }
#pragma unroll
    for (int q = 0; q < 10; ++q)
        cond[((size_t)b * 500 + t0 + q) * 320 + tid] = __float2half(tanh_f(acc[q]));
}

__global__ void k_gain(const __half* __restrict__ cond, const float* __restrict__ cgw,
                       const float* __restrict__ cgb, float* __restrict__ gains) {
    int t = blockIdx.x * 256 + threadIdx.x;
    const int total = 128 * 2000;
    if (t >= total) return;
    int s = t % 2000;
    int b = t / 2000;
    int frame = s >> 2, sub = s & 3;
    const __half* c = cond + ((size_t)b * 500 + frame) * 320 + sub * 80;
    float acc = 0.0f;
#pragma unroll 8
    for (int i = 0; i < 80; ++i) acc += __half2float(c[i]) * cgw[i];
    float g = 0.2f + 0.8f * sigm(acc + cgb[0]);
    g = fminf(20.0f, fmaxf(0.001f, g));
    gains[t] = g;
}

// ---------------------------------------------------------------------------
// 8-wide fp16 dot
// ---------------------------------------------------------------------------
DEV void dot8h(uint4 w, uint4 x, float& a0, float& a1) {
    const h2v* wv = (const h2v*)&w;
    const h2v* xv = (const h2v*)&x;
    a0 = fdot2(wv[0], xv[0], a0);
    a1 = fdot2(wv[1], xv[1], a1);
    a0 = fdot2(wv[2], xv[2], a0);
    a1 = fdot2(wv[3], xv[3], a1);
}

// ---- matvec: load (prefetch) / compute split ----
template <int OUT, int KP8, int S, int PF>
DEV void mv_load(const uint4* __restrict__ WT, uint4* pf, int tid) {
    constexpr int KS8 = KP8 / S;
    constexpr int P = (PF < KS8) ? PF : KS8;
    if (tid < OUT * S) {
        int j = tid % OUT;
        int sl = tid / OUT;
        const uint4* w = WT + (size_t)sl * KS8 * OUT + j;
#pragma unroll
        for (int k = 0; k < P; ++k) pf[k] = w[(size_t)k * OUT];
    }
}

template <int OUT, int KP8, int S, int PF>
DEV void mv_compute(const uint4* __restrict__ WT, const uint4* pf,
                    const __half* __restrict__ x, float* __restrict__ part, int tid) {
    constexpr int KS8 = KP8 / S;
    constexpr int P = (PF < KS8) ? PF : KS8;
    if (tid < OUT * S) {
        int j = tid % OUT;
        int sl = tid / OUT;
        const uint4* w = WT + (size_t)sl * KS8 * OUT + j;
        const uint4* xx = (const uint4*)x + (size_t)sl * KS8;
        float a0 = 0.0f, a1 = 0.0f;
#pragma unroll
        for (int k = 0; k < P; ++k) dot8h(pf[k], xx[k], a0, a1);
#pragma unroll
        for (int k = P; k < KS8; ++k) dot8h(w[(size_t)k * OUT], xx[k], a0, a1);
        part[tid] = a0 + a1;
    }
}

// LDS-resident matvec (no prefetch needed)
template <int OUT, int KP8, int S>
DEV void mv_compute_l(const uint4* wl, const __half* __restrict__ x,
                      float* __restrict__ part, int tid) {
    constexpr int KS8 = KP8 / S;
    if (tid < OUT * S) {
        int j = tid % OUT;
        int sl = tid / OUT;
        const uint4* w = wl + (size_t)sl * KS8 * OUT + j;
        const uint4* xx = (const uint4*)x + (size_t)sl * KS8;
        float a0 = 0.0f, a1 = 0.0f;
#pragma unroll
        for (int k = 0; k < KS8; ++k) dot8h(w[(size_t)k * OUT], xx[k], a0, a1);
        part[tid] = a0 + a1;
    }
}

// ---- GRU loads / computes (S=2 over both matrices) ----
template <int OUT, int KP8A, int KP8B, int PA, int PB>
DEV void gru_load(const uint4* __restrict__ wa, const uint4* __restrict__ wb,
                  uint4* pfa, uint4* pfb, int tid) {
    constexpr int KA = KP8A / 2, KB = KP8B / 2;
    constexpr int QA = (PA < KA) ? PA : KA;
    constexpr int QB = (PB < KB) ? PB : KB;
    if (tid < OUT * 2) {
        int j = tid % OUT, sl = tid / OUT;
        const uint4* w = wa + (size_t)sl * KA * OUT + j;
#pragma unroll
        for (int k = 0; k < QA; ++k) pfa[k] = w[(size_t)k * OUT];
        const uint4* w2 = wb + (size_t)sl * KB * OUT + j;
#pragma unroll
        for (int k = 0; k < QB; ++k) pfb[k] = w2[(size_t)k * OUT];
    }
}

template <int OUT, int KP8A, int PA>
DEV void gru_load_a(const uint4* __restrict__ wa, uint4* pfa, int tid) {
    constexpr int KA = KP8A / 2;
    constexpr int QA = (PA < KA) ? PA : KA;
    if (tid < OUT * 2) {
        int j = tid % OUT, sl = tid / OUT;
        const uint4* w = wa + (size_t)sl * KA * OUT + j;
#pragma unroll
        for (int k = 0; k < QA; ++k) pfa[k] = w[(size_t)k * OUT];
    }
}

template <int OUT, int KP8A, int KP8B, int PA, int PB>
DEV void gru_compute(const uint4* __restrict__ wa, const uint4* pfa,
                     const __half* __restrict__ xa,
                     const uint4* __restrict__ wb, const uint4* pfb,
                     const __half* __restrict__ xb,
                     float* __restrict__ pa, float* __restrict__ pb, int tid) {
    constexpr int KA = KP8A / 2, KB = KP8B / 2;
    constexpr int QA = (PA < KA) ? PA : KA;
    constexpr int QB = (PB < KB) ? PB : KB;
    if (tid < OUT * 2) {
        int j = tid % OUT, sl = tid / OUT;
        {
            const uint4* w = wa + (size_t)sl * KA * OUT + j;
            const uint4* xx = (const uint4*)xa + (size_t)sl * KA;
            float a0 = 0.0f, a1 = 0.0f;
#pragma unroll
            for (int k = 0; k < QA; ++k) dot8h(pfa[k], xx[k], a0, a1);
#pragma unroll
            for (int k = QA; k < KA; ++k) dot8h(w[(size_t)k * OUT], xx[k], a0, a1);
            pa[tid] = a0 + a1;
        }
        {
            const uint4* w = wb + (size_t)sl * KB * OUT + j;
            const uint4* xx = (const uint4*)xb + (size_t)sl * KB;
            float b0 = 0.0f, b1 = 0.0f;
#pragma unroll
            for (int k = 0; k < QB; ++k) dot8h(pfb[k], xx[k], b0, b1);
#pragma unroll
            for (int k = QB; k < KB; ++k) dot8h(w[(size_t)k * OUT], xx[k], b0, b1);
            pb[tid] = b0 + b1;
        }
    }
}

// GRU with B-matrix LDS-resident
template <int OUT, int KP8A, int KP8B, int PA>
DEV void gru_compute_bl(const uint4* __restrict__ wa, const uint4* pfa,
                        const __half* __restrict__ xa,
                        const uint4* wl, const __half* __restrict__ xb,
                        float* __restrict__ pa, float* __restrict__ pb, int tid) {
    constexpr int KA = KP8A / 2, KB = KP8B / 2;
    constexpr int QA = (PA < KA) ? PA : KA;
    if (tid < OUT * 2) {
        int j = tid % OUT, sl = tid / OUT;
        {
            const uint4* w = wa + (size_t)sl * KA * OUT + j;
            const uint4* xx = (const uint4*)xa + (size_t)sl * KA;
            float a0 = 0.0f, a1 = 0.0f;
#pragma unroll
            for (int k = 0; k < QA; ++k) dot8h(pfa[k], xx[k], a0, a1);
#pragma unroll
            for (int k = QA; k < KA; ++k) dot8h(w[(size_t)k * OUT], xx[k], a0, a1);
            pa[tid] = a0 + a1;
        }
        {
            const uint4* w = wl + (size_t)sl * KB * OUT + j;
            const uint4* xx = (const uint4*)xb + (size_t)sl * KB;
            float b0 = 0.0f, b1 = 0.0f;
#pragma unroll
            for (int k = 0; k < KB; ++k) dot8h(w[(size_t)k * OUT], xx[k], b0, b1);
            pb[tid] = b0 + b1;
        }
    }
}

template <int H>
DEV void gru_update(const float* __restrict__ pa, const float* __restrict__ pb,
                    float* __restrict__ s, __half* __restrict__ sh, int tid) {
    constexpr int OUT = 3 * H;
    if (tid < H) {
        float gi_r = pa[tid] + pa[OUT + tid];
        float gh_r = pb[tid] + pb[OUT + tid];
        float gi_z = pa[H + tid] + pa[OUT + H + tid];
        float gh_z = pb[H + tid] + pb[OUT + H + tid];
        float gi_n = pa[2 * H + tid] + pa[OUT + 2 * H + tid];
        float gh_n = pb[2 * H + tid] + pb[OUT + 2 * H + tid];
        float r = sigm(gi_r + gh_r);
        float z = sigm(gi_z + gh_z);
        float n = tanh_f(gi_n + r * gh_n);
        float v = (1.0f - z) * n + z * s[tid];
        s[tid] = v;
        sh[tid] = __float2half(v);
    }
}

// ---------------------------------------------------------------------------
// main recurrent kernel: 128 blocks x 1024 threads
// ---------------------------------------------------------------------------
__global__ __launch_bounds__(1024) void fargan_main(const float* __restrict__ ws,
                                                    const int* __restrict__ period,
                                                    const float* __restrict__ goutb,
                                                    float* __restrict__ out) {
    const int b = blockIdx.x;
    const int tid = threadIdx.x;

    const __half* cond = (const __half*)(ws + OFF_CONDH);
    const float* gains = ws + OFF_GAIN;
    const __half* whb  = (const __half*)(ws + OFF_W);
    const uint4* wFWC     = (const uint4*)(whb + W_FWC);
    const uint4* wFWCGLU  = (const uint4*)(whb + W_FWCGLU);
    const uint4* wGOUT    = (const uint4*)(whb + W_GOUT);
    const uint4* wG1IH    = (const uint4*)(whb + W_G1IH);
    const uint4* wG1HH    = (const uint4*)(whb + W_G1HH);
    const uint4* wGLU1    = (const uint4*)(whb + W_GLU1);
    const uint4* wG2IH    = (const uint4*)(whb + W_G2IH);
    const uint4* wG2HH    = (const uint4*)(whb + W_G2HH);
    const uint4* wGLU2    = (const uint4*)(whb + W_GLU2);
    const uint4* wG3IH    = (const uint4*)(whb + W_G3IH);
    const uint4* wG3HH    = (const uint4*)(whb + W_G3HH);
    const uint4* wGLU3    = (const uint4*)(whb + W_GLU3);
    const uint4* wSKIP    = (const uint4*)(whb + W_SKIP);
    const uint4* wSKIPGLU = (const uint4*)(whb + W_SKIPGLU);
    const uint4* wSIG     = (const uint4*)(whb + W_SIG);

    // LDS weight stash (128 KiB) — g2_hh + glu2
    __shared__ __align__(16) uint4 wlds[WL_TOT];

    // fp16 matvec inputs
    __shared__ __align__(16) __half xcat_h[352];
    __shared__ __align__(16) __half inb_h[272];
    __shared__ __align__(16) __half fwcpre_h[192], fwcout_h[192];
    __shared__ __align__(16) __half s1_h[160], s2_h[128], s3_h[128];
    __shared__ __align__(16) __half g1_h[160], g2_h[128], g3_h[128];
    __shared__ __align__(16) __half skipin_h[704], skippre_h[128], skipout_h[128];
    // fp32 masters
    __shared__ __align__(16) float exc[256];
    __shared__ __align__(16) float s1[160], s2[128], s3[128];
    __shared__ __align__(16) float partA[1024], partB[1024];
    __shared__ __align__(16) float fwcpre[192];
    __shared__ __align__(16) float pg[4];
    __shared__ __align__(16) float skippre[128];
    __shared__ __align__(16) float sigraw[40];

    // stash weights into LDS
    for (int i = tid; i < 6144; i += 1024) wlds[WL_G2HH + i] = wG2HH[i];
    for (int i = tid; i < 2048; i += 1024) wlds[WL_GLU2 + i] = wGLU2[i];

    // zero-init state
    for (int i = tid; i < 256; i += 1024) exc[i] = 0.0f;
    if (tid < 160) { s1[tid] = 0.0f; s1_h[tid] = __float2half(0.0f); }
    if (tid < 128) { s2[tid] = 0.0f; s3[tid] = 0.0f;
                     s2_h[tid] = __float2half(0.0f); s3_h[tid] = __float2half(0.0f); }
    if (tid < 164) xcat_h[tid] = __float2half(0.0f);
    if (tid >= 328 && tid < 352) xcat_h[tid] = __float2half(0.0f);
    if (tid >= 688 && tid < 704) skipin_h[tid] = __float2half(0.0f);
    __syncthreads();

    // prefetch buffers
    uint4 pfA[8], pfB[4], pfF[4];
    mv_load<192, 44, 4, 4>(wFWC, pfF, tid);     // fwc, first step

    for (int s = 0; s < (int)STEPS; ++s) {
        const int frame = s >> 2;
        const float gain = gains[(size_t)b * 2000 + s];
        const float ig = 1.0f / (1e-5f + gain);
        int per = period[b * 504 + 3 + frame];
        per = min(max(per, 32), 254);

        // Phase A: gather cond80, pred, prev into xcat_h
        if (tid < 80) {
            xcat_h[164 + tid] = cond[((size_t)b * 500 + frame) * 320 + (s & 3) * 80 + tid];
        } else if (tid >= 128 && tid < 172) {
            int j = tid - 128;
            int idx = 254 - per + j;
            if (idx >= 256) idx -= per;
            idx = min(255, max(0, idx));
            xcat_h[244 + j] = __float2half(exc[idx] * ig);
        } else if (tid >= 192 && tid < 232) {
            xcat_h[288 + tid - 192] = __float2half(exc[216 + tid - 192] * ig);
        }
        __syncthreads();

        // Phase B: fwc compute (uses pfF) + prefetch fwcglu
        mv_compute<192, 44, 4, 4>(wFWC, pfF, xcat_h, partA, tid);
        mv_load<192, 24, 4, 8>(wFWCGLU, pfA, tid);
        __syncthreads();
        // Phase C: reduce -> fwcpre
        if (tid < 192) {
            float a = partA[tid] + partA[192 + tid] + partA[384 + tid] + partA[576 + tid];
            float t = tanh_f(a);
            fwcpre[tid] = t;
            fwcpre_h[tid] = __float2half(t);
        }
        __syncthreads();

        // Phase D: fwcglu compute || gout || xcat shift; prefetch GRU1
        mv_compute<192, 24, 4, 8>(wFWCGLU, pfA, fwcpre_h, partA, tid);
        if (tid >= 768 && tid < 800) {
            int t2 = tid - 768;
            int j = t2 & 3, sl = t2 >> 2;
            const uint4* w = wGOUT + (sl * 3) * 4 + j;
            const uint4* xx = (const uint4*)fwcpre_h + sl * 3;
            float a0 = 0.0f, a1 = 0.0f;
#pragma unroll
            for (int k = 0; k < 3; ++k) dot8h(w[k * 4], xx[k], a0, a1);
            partB[t2] = a0 + a1;
        } else if (tid >= 832 && tid < 996) {
            xcat_h[tid - 832] = xcat_h[tid - 832 + 164];
        }
        gru_load<480, 34, 20, 8, 4>(wG1IH, wG1HH, pfA, pfB, tid);
        __syncthreads();

        // Phase E: fwcout + pg + inb(gru1)
        if (tid < 192) {
            float a = partA[tid] + partA[192 + tid] + partA[384 + tid] + partA[576 + tid];
            float v = fwcpre[tid] * sigm(a);
            __half vh = __float2half(v);
            fwcout_h[tid] = vh;
            inb_h[tid] = vh;
        } else if (tid < 232) {
            float a = goutb[0];
#pragma unroll
            for (int sl = 0; sl < 8; ++sl) a += partB[sl * 4];
            inb_h[tid] = __float2half(sigm(a) * __half2float(xcat_h[246 + tid - 192]));
        } else if (tid < 272) {
            inb_h[tid] = xcat_h[288 + tid - 232];
        } else if (tid >= 960 && tid < 964) {
            int j = tid - 960;
            float a = goutb[j];
#pragma unroll
            for (int sl = 0; sl < 8; ++sl) a += partB[sl * 4 + j];
            pg[j] = sigm(a);
        }
        __syncthreads();

        // Phase F: GRU1 compute; prefetch GLU1
        gru_compute<480, 34, 20, 8, 4>(wG1IH, pfA, inb_h, wG1HH, pfB, s1_h,
                                       partA, partB, tid);
        mv_load<160, 20, 4, 8>(wGLU1, pfA, tid);
        __syncthreads();
        // Phase G
        gru_update<160>(partA, partB, s1, s1_h, tid);
        __syncthreads();

        // Phase H: GLU1 compute; prefetch GRU2-A (B is LDS)
        mv_compute<160, 20, 4, 8>(wGLU1, pfA, s1_h, partA, tid);
        gru_load_a<384, 30, 8>(wG2IH, pfA, tid);
        __syncthreads();
        // Phase I
        if (tid < 160) {
            float a = partA[tid] + partA[160 + tid] + partA[320 + tid] + partA[480 + tid];
            float v = s1[tid] * sigm(a);
            __half vh = __float2half(v);
            g1_h[tid] = vh;
            inb_h[tid] = vh;
        } else if (tid < 200) {
            inb_h[tid] = __float2half(pg[1] * __half2float(xcat_h[246 + tid - 160]));
        } else if (tid < 240) {
            inb_h[tid] = xcat_h[288 + tid - 200];
        }
        __syncthreads();

        // Phase J: GRU2 compute (B from LDS); prefetch GRU3 (long lead over K,L,M)
        gru_compute_bl<384, 30, 16, 8>(wG2IH, pfA, inb_h, wlds + WL_G2HH, s2_h,
                                       partA, partB, tid);
        gru_load<384, 26, 16, 8, 4>(wG3IH, wG3HH, pfA, pfB, tid);
        __syncthreads();
        // Phase K
        gru_update<128>(partA, partB, s2, s2_h, tid);
        __syncthreads();

        // Phase L: GLU2 compute — LDS weights
        mv_compute_l<128, 16, 8>(wlds + WL_GLU2, s2_h, partA, tid);
        __syncthreads();
        // Phase M
        if (tid < 128) {
            float a = 0.0f;
#pragma unroll
            for (int sl = 0; sl < 8; ++sl) a += partA[sl * 128 + tid];
            float v = s2[tid] * sigm(a);
            __half vh = __float2half(v);
            g2_h[tid] = vh;
            inb_h[tid] = vh;
        } else if (tid < 168) {
            inb_h[tid] = __float2half(pg[2] * __half2float(xcat_h[246 + tid - 128]));
        } else if (tid < 208) {
            inb_h[tid] = xcat_h[288 + tid - 168];
        }
        __syncthreads();

        // Phase N: GRU3 compute; prefetch GLU3
        gru_compute<384, 26, 16, 8, 4>(wG3IH, pfA, inb_h, wG3HH, pfB, s3_h,
                                       partA, partB, tid);
        mv_load<128, 16, 8, 2>(wGLU3, pfA, tid);
        __syncthreads();
        // Phase O
        gru_update<128>(partA, partB, s3, s3_h, tid);
        __syncthreads();

        // Phase P: GLU3 compute; prefetch skip
        mv_compute<128, 16, 8, 2>(wGLU3, pfA, s3_h, partA, tid);
        mv_load<128, 88, 8, 8>(wSKIP, pfA, tid);
        __syncthreads();
        // Phase Q: skipin build
        if (tid < 128) {
            float a = 0.0f;
#pragma unroll
            for (int sl = 0; sl < 8; ++sl) a += partA[sl * 128 + tid];
            float v = s3[tid] * sigm(a);
            __half vh = __float2half(v);
            g3_h[tid] = vh;
            skipin_h[288 + tid] = vh;
        } else if (tid < 288) {
            skipin_h[tid - 128] = g1_h[tid - 128];
        } else if (tid < 416) {
            skipin_h[160 + tid - 288] = g2_h[tid - 288];
        } else if (tid < 608) {
            skipin_h[tid] = fwcout_h[tid - 416];
        } else if (tid < 648) {
            skipin_h[tid] = __float2half(pg[3] * __half2float(xcat_h[246 + tid - 608]));
        } else if (tid < 688) {
            skipin_h[tid] = xcat_h[288 + tid - 648];
        }
        __syncthreads();

        // Phase R: skip compute; prefetch skipglu
        mv_compute<128, 88, 8, 8>(wSKIP, pfA, skipin_h, partA, tid);
        mv_load<128, 16, 8, 2>(wSKIPGLU, pfA, tid);
        __syncthreads();
        // Phase S
        if (tid < 128) {
            float a = 0.0f;
#pragma unroll
            for (int sl = 0; sl < 8; ++sl) a += partA[sl * 128 + tid];
            float t = tanh_f(a);
            skippre[tid] = t;
            skippre_h[tid] = __float2half(t);
        }
        __syncthreads();

        // Phase T: skipglu compute; prefetch sig
        mv_compute<128, 16, 8, 2>(wSKIPGLU, pfA, skippre_h, partA, tid);
        mv_load<40, 16, 8, 2>(wSIG, pfA, tid);
        __syncthreads();
        // Phase U
        if (tid < 128) {
            float a = 0.0f;
#pragma unroll
            for (int sl = 0; sl < 8; ++sl) a += partA[sl * 128 + tid];
            skipout_h[tid] = __float2half(skippre[tid] * sigm(a));
        }
        __syncthreads();

        // Phase V: sig compute; prefetch next step's fwc
        mv_compute<40, 16, 8, 2>(wSIG, pfA, skipout_h, partA, tid);
        mv_load<192, 44, 4, 4>(wFWC, pfF, tid);
        __syncthreads();
        // Phase W: sig reduce + read old exc
        float keep = (tid < 216) ? exc[tid + 40] : 0.0f;
        if (tid < 40) {
            float a = 0.0f;
#pragma unroll
            for (int sl = 0; sl < 8; ++sl) a += partA[sl * 40 + tid];
            sigraw[tid] = tanh_f(a) * gain;
        }
        __syncthreads();
        // Phase X: exc shift + output
        if (tid < 216) {
            exc[tid] = keep;
        } else if (tid < 256) {
            float sv = sigraw[tid - 216];
            exc[tid] = sv;
            out[(size_t)b * 80000 + (size_t)s * 40 + (tid - 216)] = sv;
        }
        __syncthreads();
    }
}

// ---------------------------------------------------------------------------
extern "C" void kernel_launch(void* const* d_in, const int* in_sizes, int n_in,
                              void* d_out, int out_size, void* d_ws, size_t ws_size,
                              hipStream_t stream) {
    const float* features = (const float*)d_in[0];
    const int*   period   = (const int*)d_in[1];
    const float* pembed   = (const float*)d_in[2];
    const float* fd1_w    = (const float*)d_in[3];
    const float* fconv1_w = (const float*)d_in[4];
    const float* fd2_w    = (const float*)d_in[5];
    const float* cg_w     = (const float*)d_in[6];
    const float* cg_b     = (const float*)d_in[7];
    const float* fwc_w    = (const float*)d_in[8];
    const float* fwc_glu  = (const float*)d_in[9];
    const float* g1_ih    = (const float*)d_in[10];
    const float* g1_hh    = (const float*)d_in[11];
    const float* glu1_w   = (const float*)d_in[12];
    const float* g2_ih    = (const float*)d_in[13];
    const float* g2_hh    = (const float*)d_in[14];
    const float* glu2_w   = (const float*)d_in[15];
    const float* g3_ih    = (const float*)d_in[16];
    const float* g3_hh    = (const float*)d_in[17];
    const float* glu3_w   = (const float*)d_in[18];
    const float* skip_w   = (const float*)d_in[19];
    const float* skip_glu = (const float*)d_in[20];
    const float* sig_w    = (const float*)d_in[21];
    const float* gout_w   = (const float*)d_in[22];
    const float* gout_b   = (const float*)d_in[23];

    float* ws = (float*)d_ws;
    float* out = (float*)d_out;
    __half* wh = (__half*)(ws + OFF_W);

    struct PW { const float* src; size_t off; int out, k, kpad; };
    const PW pws[15] = {
        {fwc_w,    W_FWC,     192, 328, 352}, {fwc_glu, W_FWCGLU, 192, 192, 192},
        {gout_w,   W_GOUT,      4, 192, 192}, {g1_ih,   W_G1IH,   480, 272, 272},
        {g1_hh,    W_G1HH,    480, 160, 160}, {glu1_w,  W_GLU1,   160, 160, 160},
        {g2_ih,    W_G2IH,    384, 240, 240}, {g2_hh,   W_G2HH,   384, 128, 128},
        {glu2_w,   W_GLU2,    128, 128, 128}, {g3_ih,   W_G3IH,   384, 208, 208},
        {g3_hh,    W_G3HH,    384, 128, 128}, {glu3_w,  W_GLU3,   128, 128, 128},
        {skip_w,   W_SKIP,    128, 688, 704}, {skip_glu,W_SKIPGLU,128, 128, 128},
        {sig_w,    W_SIG,      40, 128, 128},
    };
    for (int i = 0; i < 15; ++i) {
        int kp8 = pws[i].kpad / 8;
        int n = pws[i].out * kp8;
        k_pack_h<<<(n + 255) / 256, 256, 0, stream>>>(pws[i].src, wh + pws[i].off,
                                                      pws[i].out, pws[i].k, kp8);
    }

    {
        int n = 128 * 502 * 64;
        k_feat<<<(n + 255) / 256, 256, 0, stream>>>(features, period, pembed, fd1_w,
                                                    ws + OFF_X);
    }
    {
        int n = 128 * 500 * 128;
        k_conv<<<(n + 255) / 256, 256, 0, stream>>>(ws + OFF_X, fconv1_w, ws + OFF_Y);
    }
    k_cond<<<128 * 50, 320, 0, stream>>>(ws + OFF_Y, fd2_w, (__half*)(ws + OFF_CONDH));
    {
        int n = 128 * 2000;
        k_gain<<<(n + 255) / 256, 256, 0, stream>>>((const __half*)(ws + OFF_CONDH),
                                                    cg_w, cg_b, ws + OFF_GAIN);
    }

    fargan_main<<<128, 1024, 0, stream>>>(ws, period, gout_b, out);
}

// Round 6
// 34107.349 us; speedup vs baseline: 2.7922x; 2.7922x over previous
//
#include <hip/hip_runtime.h>
#include <hip/hip_fp16.h>
#include <math.h>

// ---------------------------------------------------------------------------
// FARGAN core. B=128, T=504, nb_frames=500, steps=2000, SUB=40.
// Round 6: round-4 fp16/fdot2 structure (known 36.2 ms) +
//   (a) LDS-resident weights: fwcglu + glu2 + glu3 (139.3 KB stash)
//   (b) VGPR-resident g2_hh (8 named uint4 locals = 32 VGPRs, no arrays)
// NO register prefetch arrays (round-5 spill lesson).
// ---------------------------------------------------------------------------

#define DEV __device__ __forceinline__

DEV float sigm(float x) { return 1.0f / (1.0f + __expf(-x)); }
DEV float tanh_f(float x) { return 1.0f - 2.0f / (__expf(2.0f * x) + 1.0f); }

typedef _Float16 h2v __attribute__((ext_vector_type(2)));

#if defined(__has_builtin)
#if __has_builtin(__builtin_amdgcn_fdot2)
#define HAVE_FDOT2 1
#endif
#endif

DEV float fdot2(h2v a, h2v b, float c) {
#ifdef HAVE_FDOT2
    return __builtin_amdgcn_fdot2(a, b, c, false);
#else
    return c + (float)a[0] * (float)b[0] + (float)a[1] * (float)b[1];
#endif
}

// ---- workspace layout (float offsets) ----
constexpr size_t STEPS = 2000;
constexpr size_t OFF_X     = 0;          // 128*502*64 f32
constexpr size_t OFF_Y     = 4200000;    // 128*500*128 f32
constexpr size_t OFF_GAIN  = 12392000;   // 128*2000 f32
constexpr size_t OFF_CONDH = 12648000;   // 128*500*320 halves
constexpr size_t OFF_W     = 22888000;   // fp16 weights

// packed fp16 weights: OUT*KPAD halves, layout uint4[(k/8)*OUT + j]
constexpr size_t W_FWC     = 0;                       // 192 x 352
constexpr size_t W_FWCGLU  = W_FWC    + 192*352;      // 192 x 192  (LDS-resident)
constexpr size_t W_GOUT    = W_FWCGLU + 192*192;      // 4   x 192
constexpr size_t W_G1IH    = W_GOUT   + 4*192;        // 480 x 272
constexpr size_t W_G1HH    = W_G1IH   + 480*272;      // 480 x 160
constexpr size_t W_GLU1    = W_G1HH   + 480*160;      // 160 x 160
constexpr size_t W_G2IH    = W_GLU1   + 160*160;      // 384 x 240
constexpr size_t W_G2HH    = W_G2IH   + 384*240;      // 384 x 128  (VGPR-resident)
constexpr size_t W_GLU2    = W_G2HH   + 384*128;      // 128 x 128  (LDS-resident)
constexpr size_t W_G3IH    = W_GLU2   + 128*128;      // 384 x 208
constexpr size_t W_G3HH    = W_G3IH   + 384*208;      // 384 x 128
constexpr size_t W_GLU3    = W_G3HH   + 384*128;      // 128 x 128  (LDS-resident)
constexpr size_t W_SKIP    = W_GLU3   + 128*128;      // 128 x 704
constexpr size_t W_SKIPGLU = W_SKIP   + 128*704;      // 128 x 128
constexpr size_t W_SIG     = W_SKIPGLU+ 128*128;      // 40  x 128

// LDS weight stash offsets (uint4 units)
constexpr int WL_FWCGLU = 0;       // 24*192 = 4608 uint4
constexpr int WL_GLU2   = 4608;    // 16*128 = 2048
constexpr int WL_GLU3   = 6656;    // 16*128 = 2048
constexpr int WL_TOT    = 8704;    // 139,264 B

// ---------------------------------------------------------------------------
__global__ void k_pack_h(const float* __restrict__ src, __half* __restrict__ dst,
                         int OUT, int K, int KP8) {
    int t = blockIdx.x * 256 + threadIdx.x;
    if (t >= OUT * KP8) return;
    int j = t % OUT;
    int k8 = t / OUT;
    __half* d = dst + (size_t)t * 8;
#pragma unroll
    for (int i = 0; i < 8; ++i) {
        int k = k8 * 8 + i;
        d[i] = (k < K) ? __float2half(src[(size_t)j * K + k]) : __float2half(0.0f);
    }
}

// ---------------------------------------------------------------------------
// frontend (unchanged — verified)
// ---------------------------------------------------------------------------
__global__ void k_feat(const float* __restrict__ features, const int* __restrict__ period,
                       const float* __restrict__ pembed, const float* __restrict__ fd1,
                       float* __restrict__ xbuf) {
    int t = blockIdx.x * 256 + threadIdx.x;
    const int total = 128 * 502 * 64;
    if (t >= total) return;
    int o = t & 63;
    int r = t >> 6;
    int ft = r % 502;
    int b = r / 502;
    const float* f = features + ((size_t)b * 504 + ft + 2) * 20;
    int per = period[b * 504 + ft + 2];
    per = min(max(per, 32), 254);
    const float* pe = pembed + (per - 32) * 12;
    const float* w = fd1 + o * 32;
    float acc = 0.0f;
#pragma unroll
    for (int i = 0; i < 20; ++i) acc += f[i] * w[i];
#pragma unroll
    for (int i = 0; i < 12; ++i) acc += pe[i] * w[20 + i];
    xbuf[t] = tanh_f(acc);
}

__global__ void k_conv(const float* __restrict__ xbuf, const float* __restrict__ fconv1,
                       float* __restrict__ ybuf) {
    int t = blockIdx.x * 256 + threadIdx.x;
    const int total = 128 * 500 * 128;
    if (t >= total) return;
    int oc = t & 127;
    int r = t >> 7;
    int tt = r % 500;
    int b = r / 500;
    const float* xp = xbuf + ((size_t)b * 502 + tt) * 64;
    const float* w = fconv1 + oc * 192;
    float acc = 0.0f;
#pragma unroll 8
    for (int i = 0; i < 64; ++i) {
        acc += xp[i] * w[i * 3 + 0];
        acc += xp[64 + i] * w[i * 3 + 1];
        acc += xp[128 + i] * w[i * 3 + 2];
    }
    ybuf[t] = tanh_f(acc);
}

__global__ void k_cond(const float* __restrict__ ybuf, const float* __restrict__ fd2,
                       __half* __restrict__ cond) {
    int b = blockIdx.x / 50;
    int t0 = (blockIdx.x % 50) * 10;
    int tid = threadIdx.x;
    __shared__ float yl[1280];
    for (int i = tid; i < 1280; i += 320)
        yl[i] = ybuf[((size_t)b * 500 + t0) * 128 + i];
    __syncthreads();
    const float* w = fd2 + tid * 128;
    float acc[10];
#pragma unroll
    for (int q = 0; q < 10; ++q) acc[q] = 0.0f;
#pragma unroll 4
    for (int k = 0; k < 128; ++k) {
        float wv = w[k];
#pragma unroll
        for (int q = 0; q < 10; ++q) acc[q] += wv * yl[q * 128 + k];
    }
#pragma unroll
    for (int q = 0; q < 10; ++q)
        cond[((size_t)b * 500 + t0 + q) * 320 + tid] = __float2half(tanh_f(acc[q]));
}

__global__ void k_gain(const __half* __restrict__ cond, const float* __restrict__ cgw,
                       const float* __restrict__ cgb, float* __restrict__ gains) {
    int t = blockIdx.x * 256 + threadIdx.x;
    const int total = 128 * 2000;
    if (t >= total) return;
    int s = t % 2000;
    int b = t / 2000;
    int frame = s >> 2, sub = s & 3;
    const __half* c = cond + ((size_t)b * 500 + frame) * 320 + sub * 80;
    float acc = 0.0f;
#pragma unroll 8
    for (int i = 0; i < 80; ++i) acc += __half2float(c[i]) * cgw[i];
    float g = 0.2f + 0.8f * sigm(acc + cgb[0]);
    g = fminf(20.0f, fmaxf(0.001f, g));
    gains[t] = g;
}

// ---------------------------------------------------------------------------
// 8-wide fp16 dot
// ---------------------------------------------------------------------------
DEV void dot8h(uint4 w, uint4 x, float& a0, float& a1) {
    const h2v* wv = (const h2v*)&w;
    const h2v* xv = (const h2v*)&x;
    a0 = fdot2(wv[0], xv[0], a0);
    a1 = fdot2(wv[1], xv[1], a1);
    a0 = fdot2(wv[2], xv[2], a0);
    a1 = fdot2(wv[3], xv[3], a1);
}

// fp16 packed-matvec partial (global weights). No trailing barrier.
template <int OUT, int KP8, int S>
DEV void mv_partial(const uint4* __restrict__ WT, const __half* __restrict__ x,
                    float* __restrict__ part, int tid) {
    static_assert(KP8 % S == 0, "KP8 % S");
    static_assert(OUT * S <= 1024, "threads");
    constexpr int KS8 = KP8 / S;
    if (tid < OUT * S) {
        int j = tid % OUT;
        int sl = tid / OUT;
        const uint4* w = WT + (size_t)sl * KS8 * OUT + j;
        const uint4* xx = (const uint4*)x + (size_t)sl * KS8;
        float a0 = 0.0f, a1 = 0.0f;
#pragma unroll 4
        for (int k = 0; k < KS8; ++k) dot8h(w[(size_t)k * OUT], xx[k], a0, a1);
        part[tid] = a0 + a1;
    }
}

// LDS-resident matvec
template <int OUT, int KP8, int S>
DEV void mv_partial_l(const uint4* wl, const __half* __restrict__ x,
                      float* __restrict__ part, int tid) {
    constexpr int KS8 = KP8 / S;
    if (tid < OUT * S) {
        int j = tid % OUT;
        int sl = tid / OUT;
        const uint4* w = wl + (size_t)sl * KS8 * OUT + j;
        const uint4* xx = (const uint4*)x + (size_t)sl * KS8;
        float a0 = 0.0f, a1 = 0.0f;
#pragma unroll
        for (int k = 0; k < KS8; ++k) dot8h(w[(size_t)k * OUT], xx[k], a0, a1);
        part[tid] = a0 + a1;
    }
}

// GRU double partial (S=2), both matrices global
template <int OUT, int KP8A, int KP8B>
DEV void gru_partial(const uint4* __restrict__ wa, const __half* __restrict__ xa,
                     const uint4* __restrict__ wb, const __half* __restrict__ xb,
                     float* __restrict__ pa, float* __restrict__ pb, int tid) {
    static_assert((KP8A % 2 == 0) && (KP8B % 2 == 0), "even");
    constexpr int KA = KP8A / 2, KB = KP8B / 2;
    if (tid < OUT * 2) {
        int j = tid % OUT;
        int sl = tid / OUT;
        {
            const uint4* w = wa + (size_t)sl * KA * OUT + j;
            const uint4* xx = (const uint4*)xa + (size_t)sl * KA;
            float a0 = 0.0f, a1 = 0.0f;
#pragma unroll 4
            for (int k = 0; k < KA; ++k) dot8h(w[(size_t)k * OUT], xx[k], a0, a1);
            pa[tid] = a0 + a1;
        }
        {
            const uint4* w = wb + (size_t)sl * KB * OUT + j;
            const uint4* xx = (const uint4*)xb + (size_t)sl * KB;
            float b0 = 0.0f, b1 = 0.0f;
#pragma unroll 4
            for (int k = 0; k < KB; ++k) dot8h(w[(size_t)k * OUT], xx[k], b0, b1);
            pb[tid] = b0 + b1;
        }
    }
}

template <int H>
DEV void gru_update(const float* __restrict__ pa, const float* __restrict__ pb,
                    float* __restrict__ s, __half* __restrict__ sh, int tid) {
    constexpr int OUT = 3 * H;
    if (tid < H) {
        float gi_r = pa[tid] + pa[OUT + tid];
        float gh_r = pb[tid] + pb[OUT + tid];
        float gi_z = pa[H + tid] + pa[OUT + H + tid];
        float gh_z = pb[H + tid] + pb[OUT + H + tid];
        float gi_n = pa[2 * H + tid] + pa[OUT + 2 * H + tid];
        float gh_n = pb[2 * H + tid] + pb[OUT + 2 * H + tid];
        float r = sigm(gi_r + gh_r);
        float z = sigm(gi_z + gh_z);
        float n = tanh_f(gi_n + r * gh_n);
        float v = (1.0f - z) * n + z * s[tid];
        s[tid] = v;
        sh[tid] = __float2half(v);
    }
}

// ---------------------------------------------------------------------------
// main recurrent kernel: 128 blocks x 1024 threads
// ---------------------------------------------------------------------------
__global__ __launch_bounds__(1024) void fargan_main(const float* __restrict__ ws,
                                                    const int* __restrict__ period,
                                                    const float* __restrict__ goutb,
                                                    float* __restrict__ out) {
    const int b = blockIdx.x;
    const int tid = threadIdx.x;

    const __half* cond = (const __half*)(ws + OFF_CONDH);
    const float* gains = ws + OFF_GAIN;
    const __half* whb  = (const __half*)(ws + OFF_W);
    const uint4* wFWC     = (const uint4*)(whb + W_FWC);
    const uint4* wFWCGLU  = (const uint4*)(whb + W_FWCGLU);
    const uint4* wGOUT    = (const uint4*)(whb + W_GOUT);
    const uint4* wG1IH    = (const uint4*)(whb + W_G1IH);
    const uint4* wG1HH    = (const uint4*)(whb + W_G1HH);
    const uint4* wGLU1    = (const uint4*)(whb + W_GLU1);
    const uint4* wG2IH    = (const uint4*)(whb + W_G2IH);
    const uint4* wG2HH    = (const uint4*)(whb + W_G2HH);
    const uint4* wGLU2    = (const uint4*)(whb + W_GLU2);
    const uint4* wG3IH    = (const uint4*)(whb + W_G3IH);
    const uint4* wG3HH    = (const uint4*)(whb + W_G3HH);
    const uint4* wGLU3    = (const uint4*)(whb + W_GLU3);
    const uint4* wSKIP    = (const uint4*)(whb + W_SKIP);
    const uint4* wSKIPGLU = (const uint4*)(whb + W_SKIPGLU);
    const uint4* wSIG     = (const uint4*)(whb + W_SIG);

    // LDS weight stash (139.3 KB): fwcglu + glu2 + glu3
    __shared__ __align__(16) uint4 wlds[WL_TOT];

    // fp16 matvec inputs
    __shared__ __align__(16) __half xcat_h[352];
    __shared__ __align__(16) __half inb_h[272];
    __shared__ __align__(16) __half fwcpre_h[192], fwcout_h[192];
    __shared__ __align__(16) __half s1_h[160], s2_h[128], s3_h[128];
    __shared__ __align__(16) __half g1_h[160], g2_h[128], g3_h[128];
    __shared__ __align__(16) __half skipin_h[704], skippre_h[128], skipout_h[128];
    // fp32 masters
    __shared__ __align__(16) float exc[256];
    __shared__ __align__(16) float s1[160], s2[128], s3[128];
    __shared__ __align__(16) float partA[1024], partB[1024];
    __shared__ __align__(16) float fwcpre[192];
    __shared__ __align__(16) float pg[4];
    __shared__ __align__(16) float skippre[128];
    __shared__ __align__(16) float sigraw[40];

    // stash LDS weights
    for (int i = tid; i < 4608; i += 1024) wlds[WL_FWCGLU + i] = wFWCGLU[i];
    for (int i = tid; i < 2048; i += 1024) wlds[WL_GLU2 + i] = wGLU2[i];
    for (int i = tid; i < 2048; i += 1024) wlds[WL_GLU3 + i] = wGLU3[i];

    // VGPR-resident g2_hh: 8 named uint4 (32 VGPRs). Mapping matches phase J:
    // j2 = tid % 384, sl2 = tid / 384 (clamped for dead lanes), KB = 8 uint4.
    const int j2 = tid % 384;
    const int sl2 = (tid < 768) ? (tid / 384) : 0;
    const uint4* g2b = wG2HH + (size_t)sl2 * 8 * 384 + j2;
    const uint4 c0 = g2b[0 * 384];
    const uint4 c1 = g2b[1 * 384];
    const uint4 c2 = g2b[2 * 384];
    const uint4 c3 = g2b[3 * 384];
    const uint4 c4 = g2b[4 * 384];
    const uint4 c5 = g2b[5 * 384];
    const uint4 c6 = g2b[6 * 384];
    const uint4 c7 = g2b[7 * 384];

    // zero-init state
    for (int i = tid; i < 256; i += 1024) exc[i] = 0.0f;
    if (tid < 160) { s1[tid] = 0.0f; s1_h[tid] = __float2half(0.0f); }
    if (tid < 128) { s2[tid] = 0.0f; s3[tid] = 0.0f;
                     s2_h[tid] = __float2half(0.0f); s3_h[tid] = __float2half(0.0f); }
    if (tid < 164) xcat_h[tid] = __float2half(0.0f);
    if (tid >= 328 && tid < 352) xcat_h[tid] = __float2half(0.0f);
    if (tid >= 688 && tid < 704) skipin_h[tid] = __float2half(0.0f);
    __syncthreads();

    for (int s = 0; s < (int)STEPS; ++s) {
        const int frame = s >> 2;
        const float gain = gains[(size_t)b * 2000 + s];
        const float ig = 1.0f / (1e-5f + gain);
        int per = period[b * 504 + 3 + frame];
        per = min(max(per, 32), 254);

        // Phase A: gather cond80, pred, prev into xcat_h
        if (tid < 80) {
            xcat_h[164 + tid] = cond[((size_t)b * 500 + frame) * 320 + (s & 3) * 80 + tid];
        } else if (tid >= 128 && tid < 172) {
            int j = tid - 128;
            int idx = 254 - per + j;
            if (idx >= 256) idx -= per;
            idx = min(255, max(0, idx));
            xcat_h[244 + j] = __float2half(exc[idx] * ig);
        } else if (tid >= 192 && tid < 232) {
            xcat_h[288 + tid - 192] = __float2half(exc[216 + tid - 192] * ig);
        }
        __syncthreads();

        // Phase B: fwc partial (OUT=192, KP8=44, S=4)
        mv_partial<192, 44, 4>(wFWC, xcat_h, partA, tid);
        __syncthreads();
        // Phase C: reduce -> fwcpre
        if (tid < 192) {
            float a = partA[tid] + partA[192 + tid] + partA[384 + tid] + partA[576 + tid];
            float t = tanh_f(a);
            fwcpre[tid] = t;
            fwcpre_h[tid] = __float2half(t);
        }
        __syncthreads();

        // Phase D: fwcglu (LDS weights) || gout || xcat shift
        mv_partial_l<192, 24, 4>(wlds + WL_FWCGLU, fwcpre_h, partA, tid);
        if (tid >= 768 && tid < 800) {
            int t2 = tid - 768;
            int j = t2 & 3, sl = t2 >> 2;
            const uint4* w = wGOUT + (sl * 3) * 4 + j;
            const uint4* xx = (const uint4*)fwcpre_h + sl * 3;
            float a0 = 0.0f, a1 = 0.0f;
#pragma unroll
            for (int k = 0; k < 3; ++k) dot8h(w[k * 4], xx[k], a0, a1);
            partB[t2] = a0 + a1;
        } else if (tid >= 832 && tid < 996) {
            xcat_h[tid - 832] = xcat_h[tid - 832 + 164];
        }
        __syncthreads();

        // Phase E: fwcout + pg + inb(gru1)
        if (tid < 192) {
            float a = partA[tid] + partA[192 + tid] + partA[384 + tid] + partA[576 + tid];
            float v = fwcpre[tid] * sigm(a);
            __half vh = __float2half(v);
            fwcout_h[tid] = vh;
            inb_h[tid] = vh;
        } else if (tid < 232) {
            float a = goutb[0];
#pragma unroll
            for (int sl = 0; sl < 8; ++sl) a += partB[sl * 4];
            inb_h[tid] = __float2half(sigm(a) * __half2float(xcat_h[246 + tid - 192]));
        } else if (tid < 272) {
            inb_h[tid] = xcat_h[288 + tid - 232];
        } else if (tid >= 960 && tid < 964) {
            int j = tid - 960;
            float a = goutb[j];
#pragma unroll
            for (int sl = 0; sl < 8; ++sl) a += partB[sl * 4 + j];
            pg[j] = sigm(a);
        }
        __syncthreads();

        // Phase F/G: GRU1 (H=160, OUT=480; KP8 34/20)
        gru_partial<480, 34, 20>(wG1IH, inb_h, wG1HH, s1_h, partA, partB, tid);
        __syncthreads();
        gru_update<160>(partA, partB, s1, s1_h, tid);
        __syncthreads();

        // Phase H/I: GLU1 (160x160, KP8=20, S=4) + inb(gru2) build
        mv_partial<160, 20, 4>(wGLU1, s1_h, partA, tid);
        __syncthreads();
        if (tid < 160) {
            float a = partA[tid] + partA[160 + tid] + partA[320 + tid] + partA[480 + tid];
            float v = s1[tid] * sigm(a);
            __half vh = __float2half(v);
            g1_h[tid] = vh;
            inb_h[tid] = vh;
        } else if (tid < 200) {
            inb_h[tid] = __float2half(pg[1] * __half2float(xcat_h[246 + tid - 160]));
        } else if (tid < 240) {
            inb_h[tid] = xcat_h[288 + tid - 200];
        }
        __syncthreads();

        // Phase J: GRU2 (A from global, B from VGPR cache c0..c7)
        if (tid < 768) {
            constexpr int KA = 15;   // 30/2
            {
                const uint4* w = wG2IH + (size_t)sl2 * KA * 384 + j2;
                const uint4* xx = (const uint4*)inb_h + (size_t)sl2 * KA;
                float a0 = 0.0f, a1 = 0.0f;
#pragma unroll 4
                for (int k = 0; k < KA; ++k) dot8h(w[(size_t)k * 384], xx[k], a0, a1);
                partA[tid] = a0 + a1;
            }
            {
                const uint4* xb = (const uint4*)s2_h + (size_t)sl2 * 8;
                float b0 = 0.0f, b1 = 0.0f;
                dot8h(c0, xb[0], b0, b1);
                dot8h(c1, xb[1], b0, b1);
                dot8h(c2, xb[2], b0, b1);
                dot8h(c3, xb[3], b0, b1);
                dot8h(c4, xb[4], b0, b1);
                dot8h(c5, xb[5], b0, b1);
                dot8h(c6, xb[6], b0, b1);
                dot8h(c7, xb[7], b0, b1);
                partB[tid] = b0 + b1;
            }
        }
        __syncthreads();
        // Phase K
        gru_update<128>(partA, partB, s2, s2_h, tid);
        __syncthreads();

        // Phase L/M: GLU2 (LDS weights) + inb(gru3) build
        mv_partial_l<128, 16, 8>(wlds + WL_GLU2, s2_h, partA, tid);
        __syncthreads();
        if (tid < 128) {
            float a = 0.0f;
#pragma unroll
            for (int sl = 0; sl < 8; ++sl) a += partA[sl * 128 + tid];
            float v = s2[tid] * sigm(a);
            __half vh = __float2half(v);
            g2_h[tid] = vh;
            inb_h[tid] = vh;
        } else if (tid < 168) {
            inb_h[tid] = __float2half(pg[2] * __half2float(xcat_h[246 + tid - 128]));
        } else if (tid < 208) {
            inb_h[tid] = xcat_h[288 + tid - 168];
        }
        __syncthreads();

        // Phase N/O: GRU3 (H=128, OUT=384; KP8 26/16)
        gru_partial<384, 26, 16>(wG3IH, inb_h, wG3HH, s3_h, partA, partB, tid);
        __syncthreads();
        gru_update<128>(partA, partB, s3, s3_h, tid);
        __syncthreads();

        // Phase P/Q: GLU3 (LDS weights) + skipin build
        mv_partial_l<128, 16, 8>(wlds + WL_GLU3, s3_h, partA, tid);
        __syncthreads();
        if (tid < 128) {
            float a = 0.0f;
#pragma unroll
            for (int sl = 0; sl < 8; ++sl) a += partA[sl * 128 + tid];
            float v = s3[tid] * sigm(a);
            __half vh = __float2half(v);
            g3_h[tid] = vh;
            skipin_h[288 + tid] = vh;
        } else if (tid < 288) {
            skipin_h[tid - 128] = g1_h[tid - 128];
        } else if (tid < 416) {
            skipin_h[160 + tid - 288] = g2_h[tid - 288];
        } else if (tid < 608) {
            skipin_h[tid] = fwcout_h[tid - 416];
        } else if (tid < 648) {
            skipin_h[tid] = __float2half(pg[3] * __half2float(xcat_h[246 + tid - 608]));
        } else if (tid < 688) {
            skipin_h[tid] = xcat_h[288 + tid - 648];
        }
        __syncthreads();

        // Phase R/S: skip (128x688, KP8=88, S=8)
        mv_partial<128, 88, 8>(wSKIP, skipin_h, partA, tid);
        __syncthreads();
        if (tid < 128) {
            float a = 0.0f;
#pragma unroll
            for (int sl = 0; sl < 8; ++sl) a += partA[sl * 128 + tid];
            float t = tanh_f(a);
            skippre[tid] = t;
            skippre_h[tid] = __float2half(t);
        }
        __syncthreads();

        // Phase T/U: skipglu (128x128)
        mv_partial<128, 16, 8>(wSKIPGLU, skippre_h, partA, tid);
        __syncthreads();
        if (tid < 128) {
            float a = 0.0f;
#pragma unroll
            for (int sl = 0; sl < 8; ++sl) a += partA[sl * 128 + tid];
            skipout_h[tid] = __float2half(skippre[tid] * sigm(a));
        }
        __syncthreads();

        // Phase V: sig partial (40x128, KP8=16, S=8)
        mv_partial<40, 16, 8>(wSIG, skipout_h, partA, tid);
        __syncthreads();
        // Phase W: sig reduce + read old exc
        float keep = (tid < 216) ? exc[tid + 40] : 0.0f;
        if (tid < 40) {
            float a = 0.0f;
#pragma unroll
            for (int sl = 0; sl < 8; ++sl) a += partA[sl * 40 + tid];
            sigraw[tid] = tanh_f(a) * gain;
        }
        __syncthreads();
        // Phase X: exc shift + output
        if (tid < 216) {
            exc[tid] = keep;
        } else if (tid < 256) {
            float sv = sigraw[tid - 216];
            exc[tid] = sv;
            out[(size_t)b * 80000 + (size_t)s * 40 + (tid - 216)] = sv;
        }
        __syncthreads();
    }
}

// ---------------------------------------------------------------------------
extern "C" void kernel_launch(void* const* d_in, const int* in_sizes, int n_in,
                              void* d_out, int out_size, void* d_ws, size_t ws_size,
                              hipStream_t stream) {
    const float* features = (const float*)d_in[0];
    const int*   period   = (const int*)d_in[1];
    const float* pembed   = (const float*)d_in[2];
    const float* fd1_w    = (const float*)d_in[3];
    const float* fconv1_w = (const float*)d_in[4];
    const float* fd2_w    = (const float*)d_in[5];
    const float* cg_w     = (const float*)d_in[6];
    const float* cg_b     = (const float*)d_in[7];
    const float* fwc_w    = (const float*)d_in[8];
    const float* fwc_glu  = (const float*)d_in[9];
    const float* g1_ih    = (const float*)d_in[10];
    const float* g1_hh    = (const float*)d_in[11];
    const float* glu1_w   = (const float*)d_in[12];
    const float* g2_ih    = (const float*)d_in[13];
    const float* g2_hh    = (const float*)d_in[14];
    const float* glu2_w   = (const float*)d_in[15];
    const float* g3_ih    = (const float*)d_in[16];
    const float* g3_hh    = (const float*)d_in[17];
    const float* glu3_w   = (const float*)d_in[18];
    const float* skip_w   = (const float*)d_in[19];
    const float* skip_glu = (const float*)d_in[20];
    const float* sig_w    = (const float*)d_in[21];
    const float* gout_w   = (const float*)d_in[22];
    const float* gout_b   = (const float*)d_in[23];

    float* ws = (float*)d_ws;
    float* out = (float*)d_out;
    __half* wh = (__half*)(ws + OFF_W);

    struct PW { const float* src; size_t off; int out, k, kpad; };
    const PW pws[15] = {
        {fwc_w,    W_FWC,     192, 328, 352}, {fwc_glu, W_FWCGLU, 192, 192, 192},
        {gout_w,   W_GOUT,      4, 192, 192}, {g1_ih,   W_G1IH,   480, 272, 272},
        {g1_hh,    W_G1HH,    480, 160, 160}, {glu1_w,  W_GLU1,   160, 160, 160},
        {g2_ih,    W_G2IH,    384, 240, 240}, {g2_hh,   W_G2HH,   384, 128, 128},
        {glu2_w,   W_GLU2,    128, 128, 128}, {g3_ih,   W_G3IH,   384, 208, 208},
        {g3_hh,    W_G3HH,    384, 128, 128}, {glu3_w,  W_GLU3,   128, 128, 128},
        {skip_w,   W_SKIP,    128, 688, 704}, {skip_glu,W_SKIPGLU,128, 128, 128},
        {sig_w,    W_SIG,      40, 128, 128},
    };
    for (int i = 0; i < 15; ++i) {
        int kp8 = pws[i].kpad / 8;
        int n = pws[i].out * kp8;
        k_pack_h<<<(n + 255) / 256, 256, 0, stream>>>(pws[i].src, wh + pws[i].off,
                                                      pws[i].out, pws[i].k, kp8);
    }

    {
        int n = 128 * 502 * 64;
        k_feat<<<(n + 255) / 256, 256, 0, stream>>>(features, period, pembed, fd1_w,
                                                    ws + OFF_X);
    }
    {
        int n = 128 * 500 * 128;
        k_conv<<<(n + 255) / 256, 256, 0, stream>>>(ws + OFF_X, fconv1_w, ws + OFF_Y);
    }
    k_cond<<<128 * 50, 320, 0, stream>>>(ws + OFF_Y, fd2_w, (__half*)(ws + OFF_CONDH));
    {
        int n = 128 * 2000;
        k_gain<<<(n + 255) / 256, 256, 0, stream>>>((const __half*)(ws + OFF_CONDH),
                                                    cg_w, cg_b, ws + OFF_GAIN);
    }

    fargan_main<<<128, 1024, 0, stream>>>(ws, period, gout_b, out);
}